// Round 6
// baseline (121.725 us; speedup 1.0000x reference)
//
#include <hip/hip_runtime.h>

// B=8, C=256, H=W=128 fixed. n = 2^25 f32/tensor, n4 = 2^23 float4.
// Plane = 2^12 float4. Grid 2048 x 256 (exactly 32 waves/CU co-resident).
// R2 layout: block covers 256 consecutive float4 per step; iteration stride
// 2^20 float4 -> at step u, the 2048 blocks jointly cover ONE contiguous
// 8 MiB window per array (dense concurrent footprint, best DRAM locality).
// 2 phases (stride 2^19), 8 iters each -> exact cover of [0, 2^23).
// Channel = (idx >> 12) & 255 -> block-uniform, mask hoisted per phase.
//
// __launch_bounds__(256, 8): pin VGPR <= 64 -> 8 waves/SIMD. R3/R4 lesson:
// unconstrained load clustering pushed VGPR past 64 -> half occupancy, -20%.
// Per-iteration load->store (R2 shape): compiler pipelines within budget.
//
// y1 = m1[c] ? x0 : x1 ; y2 = m2[c] ? x1 : x0 ; code = m1 | (m2<<1)
// code==1 -> y1=y2=x0 (x1 not read); code==2 -> y1=y2=x1 (x0 not read).

typedef float f32x4 __attribute__((ext_vector_type(4)));

#define NCH 256

__device__ __forceinline__ void phase_stream(
    int base, unsigned int m,
    const f32x4* __restrict__ x0, const f32x4* __restrict__ x1,
    f32x4* __restrict__ y1, f32x4* __restrict__ y2)
{
    if (m == 1u) {                 // y1 = y2 = x0 (x1 not read)
#pragma unroll
        for (int u = 0; u < 8; ++u) {
            const int i = base + (u << 20);
            f32x4 a = __builtin_nontemporal_load(&x0[i]);
            __builtin_nontemporal_store(a, &y1[i]);
            __builtin_nontemporal_store(a, &y2[i]);
        }
    } else if (m == 2u) {          // y1 = y2 = x1 (x0 not read)
#pragma unroll
        for (int u = 0; u < 8; ++u) {
            const int i = base + (u << 20);
            f32x4 b = __builtin_nontemporal_load(&x1[i]);
            __builtin_nontemporal_store(b, &y1[i]);
            __builtin_nontemporal_store(b, &y2[i]);
        }
    } else if (m == 3u) {          // y1 = x0, y2 = x1
#pragma unroll
        for (int u = 0; u < 8; ++u) {
            const int i = base + (u << 20);
            f32x4 a = __builtin_nontemporal_load(&x0[i]);
            f32x4 b = __builtin_nontemporal_load(&x1[i]);
            __builtin_nontemporal_store(a, &y1[i]);
            __builtin_nontemporal_store(b, &y2[i]);
        }
    } else {                       // m==0: y1 = x1, y2 = x0
#pragma unroll
        for (int u = 0; u < 8; ++u) {
            const int i = base + (u << 20);
            f32x4 a = __builtin_nontemporal_load(&x0[i]);
            f32x4 b = __builtin_nontemporal_load(&x1[i]);
            __builtin_nontemporal_store(b, &y1[i]);
            __builtin_nontemporal_store(a, &y2[i]);
        }
    }
}

__global__ __launch_bounds__(256, 8) void fused_kernel(
    const float* __restrict__ w1, const float* __restrict__ w2,
    const f32x4* __restrict__ x0, const f32x4* __restrict__ x1,
    f32x4* __restrict__ y1, f32x4* __restrict__ y2)
{
    __shared__ float redf[16];          // min1[4] max1[4] min2[4] max2[4]
    __shared__ int   hist1[NCH], hist2[NCH];
    __shared__ int   redi[8];           // best1[4] best2[4]
    __shared__ unsigned int code_s[NCH];

    const int t    = threadIdx.x;       // one channel each
    const int lane = t & 63;
    const int wid  = t >> 6;

    // ---- fused mask preamble: both weight vectors, 4 barriers ----
    const float b1 = fabsf(w1[t]);
    const float b2 = fabsf(w2[t]);

    float mn1 = b1, mx1 = b1, mn2 = b2, mx2 = b2;
#pragma unroll
    for (int off = 32; off > 0; off >>= 1) {
        mn1 = fminf(mn1, __shfl_xor(mn1, off));
        mx1 = fmaxf(mx1, __shfl_xor(mx1, off));
        mn2 = fminf(mn2, __shfl_xor(mn2, off));
        mx2 = fmaxf(mx2, __shfl_xor(mx2, off));
    }
    if (lane == 0) {
        redf[wid] = mn1; redf[4 + wid] = mx1;
        redf[8 + wid] = mn2; redf[12 + wid] = mx2;
    }
    hist1[t] = 0; hist2[t] = 0;
    __syncthreads();

    const float wmin1 = fminf(fminf(redf[0], redf[1]), fminf(redf[2], redf[3]));
    const float wmax1 = fmaxf(fmaxf(redf[4], redf[5]), fmaxf(redf[6], redf[7]));
    const float wmin2 = fminf(fminf(redf[8], redf[9]), fminf(redf[10], redf[11]));
    const float wmax2 = fmaxf(fmaxf(redf[12], redf[13]), fmaxf(redf[14], redf[15]));

    // torch.histc semantics, f32 op order identical to reference
    int idx1 = (int)floorf((b1 - wmin1) / (wmax1 - wmin1) * 256.0f);
    idx1 = idx1 < 0 ? 0 : (idx1 > 255 ? 255 : idx1);
    atomicAdd(&hist1[idx1], 1);
    int idx2 = (int)floorf((b2 - wmin2) / (wmax2 - wmin2) * 256.0f);
    idx2 = idx2 < 0 ? 0 : (idx2 > 255 ? 255 : idx2);
    atomicAdd(&hist2[idx2], 1);
    __syncthreads();

    // first i with diff[i] <= 0 < diff[i+1]; fallback 0
    int best1 = 0x7fffffff, best2 = 0x7fffffff;
    if (t < 254) {
        int d0 = hist1[t + 1] - hist1[t];
        int d1 = hist1[t + 2] - hist1[t + 1];
        if (d0 <= 0 && d1 > 0) best1 = t;
        d0 = hist2[t + 1] - hist2[t];
        d1 = hist2[t + 2] - hist2[t + 1];
        if (d0 <= 0 && d1 > 0) best2 = t;
    }
#pragma unroll
    for (int off = 32; off > 0; off >>= 1) {
        best1 = min(best1, __shfl_xor(best1, off));
        best2 = min(best2, __shfl_xor(best2, off));
    }
    if (lane == 0) { redi[wid] = best1; redi[4 + wid] = best2; }
    __syncthreads();

    int i1 = min(min(redi[0], redi[1]), min(redi[2], redi[3]));
    int i2 = min(min(redi[4], redi[5]), min(redi[6], redi[7]));
    i1 = (i1 == 0x7fffffff) ? 0 : i1;
    i2 = (i2 == 0x7fffffff) ? 0 : i2;

    const float thr1 = wmin1 + (float)(i1 + 2) * (wmax1 - wmin1) / 256.0f;
    const float thr2 = wmin2 + (float)(i2 + 2) * (wmax2 - wmin2) / 256.0f;

    code_s[t] = (b1 >= thr1 ? 1u : 0u) | (b2 >= thr2 ? 2u : 0u);
    __syncthreads();

    // ---- streaming: channel block-uniform per phase (R2 strided layout) ----
    const int c0 = blockIdx.x >> 4;               // 16 blocks/plane, c0 in [0,128)
    const unsigned int m0 = code_s[c0];
    const unsigned int m1 = code_s[c0 + 128];
    const int base = blockIdx.x * 256 + t;        // < 2^19

    phase_stream(base,             m0, x0, x1, y1, y2);
    phase_stream(base + (1 << 19), m1, x0, x1, y1, y2);
}

extern "C" void kernel_launch(void* const* d_in, const int* in_sizes, int n_in,
                              void* d_out, int out_size, void* d_ws, size_t ws_size,
                              hipStream_t stream)
{
    const float* x0 = (const float*)d_in[0];
    const float* x1 = (const float*)d_in[1];
    const float* w1 = (const float*)d_in[2];
    const float* w2 = (const float*)d_in[3];

    const long long n4 = (long long)in_sizes[0] / 4;   // 8,388,608 = 2^23

    f32x4* y1 = (f32x4*)d_out;
    f32x4* y2 = y1 + n4;

    fused_kernel<<<2048, 256, 0, stream>>>(
        w1, w2, (const f32x4*)x0, (const f32x4*)x1, y1, y2);
}

// Round 7
// 100.176 us; speedup vs baseline: 1.2151x; 1.2151x over previous
//
#include <hip/hip_runtime.h>

// B=8, C=256, H=W=128 fixed. n = 2^25 f32/tensor, n4 = 2^23 float4.
// Plane = 2^12 float4. Grid 2048 x 256. R2 strided layout: block covers 256
// consecutive float4 per step; iteration stride 2^20 float4; 2 phases
// (stride 2^19), 8 guarded iters each. Channel = block-uniform per phase.
//
// IMPORTANT (R2-R6 evidence): keep the per-iteration `i < n4` guard even
// though it is always true. It compiles to an exec-mask toggle that fences
// the scheduler into a clean per-iteration load->store pipeline (100.5 us).
// Removing it (R3/R4/R6) regressed to 119-122 us regardless of source-level
// clustering or __launch_bounds__ caps. Do NOT "simplify" this.
//
// y1 = m1[c] ? x0 : x1 ; y2 = m2[c] ? x1 : x0 ; code = m1 | (m2<<1)
// code==1 -> y1=y2=x0 (x1 not read); code==2 -> y1=y2=x1 (x0 not read).

typedef float f32x4 __attribute__((ext_vector_type(4)));

#define NCH 256

__device__ __forceinline__ void stream8(
    int base, unsigned int m, long long n4,
    const f32x4* __restrict__ x0, const f32x4* __restrict__ x1,
    f32x4* __restrict__ y1, f32x4* __restrict__ y2)
{
    if (m == 1u) {            // y1 = x0, y2 = x0  (x1 never read)
#pragma unroll
        for (int u = 0; u < 8; ++u) {
            long long i = (long long)base + ((long long)u << 20);
            if (i < n4) {
                f32x4 a = __builtin_nontemporal_load(&x0[i]);
                __builtin_nontemporal_store(a, &y1[i]);
                __builtin_nontemporal_store(a, &y2[i]);
            }
        }
    } else if (m == 2u) {     // y1 = x1, y2 = x1  (x0 never read)
#pragma unroll
        for (int u = 0; u < 8; ++u) {
            long long i = (long long)base + ((long long)u << 20);
            if (i < n4) {
                f32x4 b = __builtin_nontemporal_load(&x1[i]);
                __builtin_nontemporal_store(b, &y1[i]);
                __builtin_nontemporal_store(b, &y2[i]);
            }
        }
    } else if (m == 3u) {     // y1 = x0, y2 = x1
#pragma unroll
        for (int u = 0; u < 8; ++u) {
            long long i = (long long)base + ((long long)u << 20);
            if (i < n4) {
                f32x4 a = __builtin_nontemporal_load(&x0[i]);
                f32x4 b = __builtin_nontemporal_load(&x1[i]);
                __builtin_nontemporal_store(a, &y1[i]);
                __builtin_nontemporal_store(b, &y2[i]);
            }
        }
    } else {                  // m==0: y1 = x1, y2 = x0
#pragma unroll
        for (int u = 0; u < 8; ++u) {
            long long i = (long long)base + ((long long)u << 20);
            if (i < n4) {
                f32x4 a = __builtin_nontemporal_load(&x0[i]);
                f32x4 b = __builtin_nontemporal_load(&x1[i]);
                __builtin_nontemporal_store(b, &y1[i]);
                __builtin_nontemporal_store(a, &y2[i]);
            }
        }
    }
}

__global__ __launch_bounds__(256) void fused_kernel(
    const float* __restrict__ w1, const float* __restrict__ w2,
    const f32x4* __restrict__ x0, const f32x4* __restrict__ x1,
    f32x4* __restrict__ y1, f32x4* __restrict__ y2, long long n4)
{
    __shared__ float redf[16];          // min1[4] max1[4] min2[4] max2[4]
    __shared__ int   hist1[NCH], hist2[NCH];
    __shared__ int   redi[8];           // best1[4] best2[4]
    __shared__ unsigned int code_s[NCH];

    const int t    = threadIdx.x;       // one channel each
    const int lane = t & 63;
    const int wid  = t >> 6;

    // ---- fused mask preamble: both weight vectors, 4 barriers ----
    const float b1 = fabsf(w1[t]);
    const float b2 = fabsf(w2[t]);

    float mn1 = b1, mx1 = b1, mn2 = b2, mx2 = b2;
#pragma unroll
    for (int off = 32; off > 0; off >>= 1) {
        mn1 = fminf(mn1, __shfl_xor(mn1, off));
        mx1 = fmaxf(mx1, __shfl_xor(mx1, off));
        mn2 = fminf(mn2, __shfl_xor(mn2, off));
        mx2 = fmaxf(mx2, __shfl_xor(mx2, off));
    }
    if (lane == 0) {
        redf[wid] = mn1; redf[4 + wid] = mx1;
        redf[8 + wid] = mn2; redf[12 + wid] = mx2;
    }
    hist1[t] = 0; hist2[t] = 0;
    __syncthreads();

    const float wmin1 = fminf(fminf(redf[0], redf[1]), fminf(redf[2], redf[3]));
    const float wmax1 = fmaxf(fmaxf(redf[4], redf[5]), fmaxf(redf[6], redf[7]));
    const float wmin2 = fminf(fminf(redf[8], redf[9]), fminf(redf[10], redf[11]));
    const float wmax2 = fmaxf(fmaxf(redf[12], redf[13]), fmaxf(redf[14], redf[15]));

    // torch.histc semantics, f32 op order identical to reference
    int idx1 = (int)floorf((b1 - wmin1) / (wmax1 - wmin1) * 256.0f);
    idx1 = idx1 < 0 ? 0 : (idx1 > 255 ? 255 : idx1);
    atomicAdd(&hist1[idx1], 1);
    int idx2 = (int)floorf((b2 - wmin2) / (wmax2 - wmin2) * 256.0f);
    idx2 = idx2 < 0 ? 0 : (idx2 > 255 ? 255 : idx2);
    atomicAdd(&hist2[idx2], 1);
    __syncthreads();

    // first i with diff[i] <= 0 < diff[i+1]; fallback 0
    int best1 = 0x7fffffff, best2 = 0x7fffffff;
    if (t < 254) {
        int d0 = hist1[t + 1] - hist1[t];
        int d1 = hist1[t + 2] - hist1[t + 1];
        if (d0 <= 0 && d1 > 0) best1 = t;
        d0 = hist2[t + 1] - hist2[t];
        d1 = hist2[t + 2] - hist2[t + 1];
        if (d0 <= 0 && d1 > 0) best2 = t;
    }
#pragma unroll
    for (int off = 32; off > 0; off >>= 1) {
        best1 = min(best1, __shfl_xor(best1, off));
        best2 = min(best2, __shfl_xor(best2, off));
    }
    if (lane == 0) { redi[wid] = best1; redi[4 + wid] = best2; }
    __syncthreads();

    int i1 = min(min(redi[0], redi[1]), min(redi[2], redi[3]));
    int i2 = min(min(redi[4], redi[5]), min(redi[6], redi[7]));
    i1 = (i1 == 0x7fffffff) ? 0 : i1;
    i2 = (i2 == 0x7fffffff) ? 0 : i2;

    const float thr1 = wmin1 + (float)(i1 + 2) * (wmax1 - wmin1) / 256.0f;
    const float thr2 = wmin2 + (float)(i2 + 2) * (wmax2 - wmin2) / 256.0f;

    code_s[t] = (b1 >= thr1 ? 1u : 0u) | (b2 >= thr2 ? 2u : 0u);
    __syncthreads();

    // ---- streaming: channel block-uniform per phase (R2 guarded layout) ----
    const int c0 = blockIdx.x >> 4;               // 16 blocks/plane, c0 in [0,128)
    const unsigned int m0 = code_s[c0];
    const unsigned int m1 = code_s[c0 + 128];
    const int base = blockIdx.x * 256 + t;        // < 2^19

    stream8(base,             m0, n4, x0, x1, y1, y2);
    stream8(base + (1 << 19), m1, n4, x0, x1, y1, y2);
}

extern "C" void kernel_launch(void* const* d_in, const int* in_sizes, int n_in,
                              void* d_out, int out_size, void* d_ws, size_t ws_size,
                              hipStream_t stream)
{
    const float* x0 = (const float*)d_in[0];
    const float* x1 = (const float*)d_in[1];
    const float* w1 = (const float*)d_in[2];
    const float* w2 = (const float*)d_in[3];

    const long long n4 = (long long)in_sizes[0] / 4;   // 8,388,608 = 2^23

    f32x4* y1 = (f32x4*)d_out;
    f32x4* y2 = y1 + n4;

    fused_kernel<<<2048, 256, 0, stream>>>(
        w1, w2, (const f32x4*)x0, (const f32x4*)x1, y1, y2, n4);
}